// Round 8
// baseline (144.506 us; speedup 1.0000x reference)
//
#include <hip/hip_runtime.h>
#include <float.h>

// VectorQuantizer: x [64,64,32,32] f32, weight [1024,64] f32
// out[n] = weight[argmin_k ||x_n - w_k||^2]
// score = 0.5||w||^2 + (-x).w via split-bf16 MFMA (6-step, lo*lo dropped).
// R21 (resubmit — R7 bench was GPUAcquisitionTimeout, never measured).
// LDS-shrink occupancy attack ON the staged structure.
// R20 post-mortem: staging + validated deltas -> 48.5us, MfmaUtil 20%,
// but LDS 67KB => 2 blocks/CU => 2 waves/SIMD; ~50% stall is dep-latency
// with no independent work to hide it. Cross-BLOCK overlap (independent,
// never barrier-synced) is the hiding mechanism the staged path can use.
//   (1) CPK 128->64 (16 chunks): dbuf 2x16KB, total LDS 37.9KB ->
//       4 blocks/CU (152KB/CU). Same total MFMA (768/wave), folds (512),
//       ds_reads (128 b128), DMA bytes; only +8 cheap barriers.
//   (2) acc[4][4]->acc[4][2]: -32 regs => ~100 unified => 16 waves/CU
//       legal (m69 pool). __launch_bounds__(256,4): budget 128 > ~100
//       demand — safe, unlike R17's 140-demand spill.
//   (3) Everything else = R20: XOR-swizzled WEg staging (k&15=r16
//       invariant preserved), 6-step product, short8 XE writes, redk-less
//       epilogue, eps 7e-4+5e-5|B1|, inline exact rescue.
#define NLAT   65536
#define KCODES 1024
#define DIM    64
#define HW     1024
#define LPB    128
#define CPK    64
#define NCHUNK 16
#define XROW   136          // XE padded row (shorts): 272 B

typedef float f32x4 __attribute__((ext_vector_type(4)));
typedef short short8 __attribute__((ext_vector_type(8)));

static __device__ __forceinline__ unsigned short f2bf(float f) {
    unsigned int u = __float_as_uint(f);
    return (unsigned short)((u + 0x7fffu + ((u >> 16) & 1u)) >> 16);   // RNE
}
static __device__ __forceinline__ float bf2f(unsigned short h) {
    return __uint_as_float(((unsigned int)h) << 16);
}
static __device__ __forceinline__ void async_cp16(const void* g, void* l) {
    __builtin_amdgcn_global_load_lds(
        (const __attribute__((address_space(1))) unsigned int*)g,
        (__attribute__((address_space(3))) unsigned int*)l, 16, 0, 0);
}

// ---------------------------------------------------------------------------
// Prep: one WAVE per code (grid 256 x 256 thr). Lane d loads w[k][d]
// (coalesced), shuffle-reduces the norm, writes hi/lo shorts into the
// XOR-swizzled row: logical seg L (L<8: hi, L>=8: lo), phys = L ^ (k & 15).
__global__ __launch_bounds__(256)
void vq_prep(const float* __restrict__ w, unsigned short* __restrict__ WEg,
             float* __restrict__ wn) {
    const int wave = threadIdx.x >> 6, lane = threadIdx.x & 63;
    const int k = blockIdx.x * 4 + wave;
    float v = w[(size_t)k * DIM + lane];
    float s = v * v;
    #pragma unroll
    for (int m = 32; m > 0; m >>= 1) s += __shfl_xor(s, m, 64);
    if (lane == 0) wn[k] = 0.5f * s;
    unsigned short h = f2bf(v);
    unsigned short l = f2bf(v - bf2f(h));
    unsigned short* row = WEg + (size_t)k * 128;
    const int j = lane & 7, Lh = lane >> 3, Ll = 8 + (lane >> 3);
    row[(((Lh ^ (k & 15)) << 3) | j)] = h;
    row[(((Ll ^ (k & 15)) << 3) | j)] = l;
}

// ---------------------------------------------------------------------------
// Main: 512 blocks x 256 thr (2 latent-halves x 2 code-halves). Wave tile
// 64 lats x 32 codes per 64-code chunk; A-frags (negated x) pinned in regs;
// B double-buffered in LDS via async DMA; inline exact rescue; gather.
__global__ __launch_bounds__(256, 4)
void vq_main(const float* __restrict__ x, const float* __restrict__ w,
             const unsigned short* __restrict__ WEg, const float* __restrict__ wn,
             float* __restrict__ out) {
    __shared__ __align__(16) char smem[37904];
    unsigned short* XE = (unsigned short*)smem;        // [128][136] (phase 0 only)
    char* wbuf0 = smem;                                // 16KB B buf (even chunks)
    char* wbuf1 = smem + 16384;                        // 16KB B buf (odd chunks)
    float* red  = (float*)smem;                        // [32][129] f32 (post-K)
    float* hb1  = (float*)(smem + 34816);              // [2][128] half-reduced score
    int*   hbk  = (int*)(smem + 35840);                // [2][128] half-reduced k
    int*   bfin = (int*)(smem + 36864);                // [128] winner k
    int*   amb  = (int*)(smem + 37376);                // [128] ambiguous lat ids
    int*   ambn = (int*)(smem + 37888);                // count

    const int tid  = threadIdx.x;
    const int wave = tid >> 6, lane = tid & 63;
    const int r16  = lane & 15, quad = lane >> 4;
    const int LH = wave & 1, CH = wave >> 1;   // CH: 32-code half of each 64-chunk

    const int blk = blockIdx.x;
    const int b   = blk >> 3;
    const int hw0 = (blk & 7) * LPB;

    if (tid == 0) ambn[0] = 0;

    // Phase 0: convert NEGATED x tile -> XE[lat][hi 0..63 | lo 64..127].
    {
        const int lat  = tid & 127;
        const int half = tid >> 7;
        const float* xb = x + (size_t)b * (DIM * HW) + hw0 + lat;
        #pragma unroll
        for (int g = 0; g < 4; ++g) {
            short8 hv, lv;
            #pragma unroll
            for (int j = 0; j < 8; ++j) {
                int chn = half * 32 + g * 8 + j;
                float v = -xb[chn * HW];          // negate: score = wn + (-x).w
                unsigned short h = f2bf(v);
                hv[j] = (short)h;
                lv[j] = (short)f2bf(v - bf2f(h));
            }
            *(short8*)&XE[lat * XROW + half * 32 + g * 8]      = hv;
            *(short8*)&XE[lat * XROW + 64 + half * 32 + g * 8] = lv;
        }
    }
    __syncthreads();

    // A-frags: span 0=hi d0-31, 1=hi d32-63, 2=lo d0-31, 3=lo d32-63
    short8 areg[4][4];
    #pragma unroll
    for (int lt = 0; lt < 4; ++lt)
        #pragma unroll
        for (int p = 0; p < 4; ++p)
            areg[lt][p] = *(const short8*)&XE[(LH * 64 + lt * 16 + r16) * XROW + p * 32 + quad * 8];
    __syncthreads();   // XE dead -> wbuf may overwrite

    // Prefetch chunk 0 into wbuf0 (drained by the first loop-top barrier)
    {
        const char* gsrc = (const char*)WEg + wave * 4096 + lane * 16;
        char* ldst = wbuf0 + wave * 4096;
        #pragma unroll
        for (int i = 0; i < 4; ++i) async_cp16(gsrc + i * 1024, ldst + i * 1024);
    }

    float b1[16], b2[16];
    #pragma unroll
    for (int sl = 0; sl < 16; ++sl) { b1[sl] = FLT_MAX; b2[sl] = FLT_MAX; }

    for (int ch = 0; ch < NCHUNK; ++ch) {
        __syncthreads();   // drains chunk-ch DMA (issued one full phase ago)
        if (ch + 1 < NCHUNK) {   // prefetch next chunk into the other buffer
            const char* gsrc = (const char*)WEg + (ch + 1) * 16384 + wave * 4096 + lane * 16;
            char* ldst = (((ch + 1) & 1) ? wbuf1 : wbuf0) + wave * 4096;
            #pragma unroll
            for (int i = 0; i < 4; ++i) async_cp16(gsrc + i * 1024, ldst + i * 1024);
        }
        const char* cbuf = (ch & 1) ? wbuf1 : wbuf0;
        const int kb = ch * CPK;

        float wnv[2] = {wn[kb + CH * 32 + r16], wn[kb + CH * 32 + 16 + r16]};
        f32x4 acc[4][2];
        #pragma unroll
        for (int lt = 0; lt < 4; ++lt)
            #pragma unroll
            for (int ct = 0; ct < 2; ++ct) {
                acc[lt][ct][0] = wnv[ct]; acc[lt][ct][1] = wnv[ct];
                acc[lt][ct][2] = wnv[ct]; acc[lt][ct][3] = wnv[ct];
            }

        // 6-step split product (lo*lo dropped; covered by rescue eps).
        // W spans: 0=hi d0-31, 1=hi d32-63, 2=lo d0-31, 3=lo d32-63.
        const int AI[6]  = {0, 1, 0, 2, 1, 3};
        const int WSp[6] = {2, 3, 0, 0, 1, 1};
        short8 bf[2];
        #pragma unroll
        for (int s = 0; s < 6; ++s) {
            if (s == 0 || WSp[s] != WSp[s - 1]) {
                #pragma unroll
                for (int ct = 0; ct < 2; ++ct) {
                    int rr = CH * 32 + ct * 16 + r16;      // row in chunk; k&15==r16
                    int seg = (WSp[s] * 4 + quad) ^ r16;   // matches prep swizzle
                    bf[ct] = *(const short8*)(cbuf + rr * 256 + seg * 16);
                }
            }
            #pragma unroll
            for (int lt = 0; lt < 4; ++lt)
                #pragma unroll
                for (int ct = 0; ct < 2; ++ct)
                    acc[lt][ct] = __builtin_amdgcn_mfma_f32_16x16x32_bf16(
                        areg[lt][AI[s]], bf[ct], acc[lt][ct], 0, 0, 0);
        }

        // Fold (3 ops/score): pack vid=(ch<<1)|ct in low 5 mantissa bits;
        // b2 = med3(b1,b2,p) exact top-2 update; b1 = min(b1,p).
        #pragma unroll
        for (int ct = 0; ct < 2; ++ct) {
            const unsigned vid = (unsigned)((ch << 1) | ct);
            #pragma unroll
            for (int lt = 0; lt < 4; ++lt)
                #pragma unroll
                for (int r = 0; r < 4; ++r) {
                    int sl = lt * 4 + r;
                    float p = __uint_as_float(
                        (__float_as_uint(acc[lt][ct][r]) & 0xFFFFFFE0u) | vid);
                    b2[sl] = __builtin_amdgcn_fmed3f(b1[sl], b2[sl], p);
                    b1[sl] = fminf(b1[sl], p);
                }
        }
    }

    // ---- Epilogue phase 1: argmin over 32 contributors per latent ----
    // Raw (vid-embedded) scores stored; k reconstructed from (vid,cid).
    // Any masked-score tie lands under eps => exact rescue.
    __syncthreads();   // wbuf dead -> red alias safe
    const int cid = CH * 16 + r16;   // 32 contributors per latent
    int kslot[16];
    #pragma unroll
    for (int lt = 0; lt < 4; ++lt)
        #pragma unroll
        for (int r = 0; r < 4; ++r) {
            int sl = lt * 4 + r;
            unsigned ub = __float_as_uint(b1[sl]);
            int vid = (int)(ub & 31u);
            kslot[sl] = (vid >> 1) * 64 + CH * 32 + (vid & 1) * 16 + r16;
            int lat = LH * 64 + lt * 16 + quad * 4 + r;
            red[cid * 129 + lat] = b1[sl];           // raw, vid kept
        }
    __syncthreads();
    // 2x-parallel: all 256 threads reduce 16 contributors each
    {
        const int lat = tid & 127, hf = tid >> 7;
        const int c0 = hf * 16;
        float s1 = red[c0 * 129 + lat]; int c1 = c0;
        #pragma unroll 4
        for (int c = 1; c < 16; ++c) {
            float s = red[(c0 + c) * 129 + lat];
            if (s < s1) { s1 = s; c1 = c0 + c; }
        }
        unsigned ub = __float_as_uint(s1);
        int vid = (int)(ub & 31u);
        hb1[hf * 128 + lat] = s1;
        hbk[hf * 128 + lat] = (vid >> 1) * 64 + (c1 >> 4) * 32 + (vid & 1) * 16 + (c1 & 15);
    }
    __syncthreads();
    float B1 = 0.f;
    if (tid < LPB) {
        float sA = hb1[tid];       int kA = hbk[tid];
        float sB = hb1[128 + tid]; int kB = hbk[128 + tid];
        if (sB < sA) { sA = sB; kA = kB; }
        B1 = sA; bfin[tid] = kA;
    }
    __syncthreads();
    // Phase 2: global 2nd best = min over (holder-of-winner-k ? b2 : b1)
    #pragma unroll
    for (int lt = 0; lt < 4; ++lt)
        #pragma unroll
        for (int r = 0; r < 4; ++r) {
            int sl = lt * 4 + r;
            int lat = LH * 64 + lt * 16 + quad * 4 + r;
            red[cid * 129 + lat] = (kslot[sl] == bfin[lat]) ? b2[sl] : b1[sl];
        }
    __syncthreads();
    {
        const int lat = tid & 127, hf = tid >> 7;
        float m = red[(hf * 16) * 129 + lat];
        #pragma unroll 4
        for (int c = 1; c < 16; ++c) m = fminf(m, red[(hf * 16 + c) * 129 + lat]);
        hb1[hf * 128 + lat] = m;
    }
    __syncthreads();
    if (tid < LPB) {
        float f2 = fminf(hb1[tid], hb1[128 + tid]);
        // eps: split double-rounding + fp32 accum + vid truncation + dropped
        // lo*lo term (<= ~1e-4 worst): base 7e-4, rel 5e-5.
        float eps = 7.0e-4f + 5.0e-5f * fabsf(B1);
        if (f2 - B1 < eps) {
            int pos = atomicAdd(ambn, 1);
            amb[pos] = tid;
        }
    }
    __syncthreads();

    // ---- Inline exact rescue: one wave per ambiguous latent ----
    {
        const int na = ambn[0];
        for (int e = wave; e < na; e += 4) {
            const int lat = amb[e];
            const float* xp = x + (size_t)b * (DIM * HW) + hw0 + lat;
            float xs[DIM];
            #pragma unroll
            for (int d = 0; d < DIM; ++d) xs[d] = xp[d * HW];  // wave-uniform
            float bb = FLT_MAX; int bi = 0;
            #pragma unroll 2
            for (int c = 0; c < 16; ++c) {
                int k = c * 64 + lane;
                const float4* wr = (const float4*)(w + (size_t)k * DIM);
                float a0 = 0.f, a1 = 0.f, a2 = 0.f, a3 = 0.f;
                #pragma unroll
                for (int j = 0; j < 16; ++j) {
                    float4 v = wr[j];
                    a0 += xs[4 * j]     * v.x;  a1 += xs[4 * j + 1] * v.y;
                    a2 += xs[4 * j + 2] * v.z;  a3 += xs[4 * j + 3] * v.w;
                }
                float s = wn[k] - ((a0 + a1) + (a2 + a3));
                if (s < bb) { bb = s; bi = k; }
            }
            #pragma unroll
            for (int off = 32; off > 0; off >>= 1) {   // lex (score,k) argmin
                float ob = __shfl_down(bb, off);
                int   oi = __shfl_down(bi, off);
                if (ob < bb || (ob == bb && oi < bi)) { bb = ob; bi = oi; }
            }
            if (lane == 0) bfin[lat] = bi;
        }
    }
    __syncthreads();

    // ---- Gather: out[n][:] = w[bfin][:]  (coalesced float4) ----
    float* outp = out + (size_t)blk * (LPB * DIM);
    #pragma unroll
    for (int r = 0; r < 8; ++r) {
        int idx = r * 256 + tid;
        int row = idx >> 4, seg = idx & 15;
        int code = bfin[row];
        *(float4*)&outp[idx * 4] = *(const float4*)&w[(size_t)code * DIM + seg * 4];
    }
}

extern "C" void kernel_launch(void* const* d_in, const int* in_sizes, int n_in,
                              void* d_out, int out_size, void* d_ws, size_t ws_size,
                              hipStream_t stream) {
    const float* x = (const float*)d_in[0];
    const float* w = (const float*)d_in[1];
    float* out = (float*)d_out;
    unsigned short* WEg = (unsigned short*)d_ws;                  // 262144 B (swizzled)
    float* wn = (float*)((char*)d_ws + 262144);                   // 4096 B

    vq_prep<<<KCODES / 4, 256, 0, stream>>>(w, WEg, wn);
    vq_main<<<NLAT / LPB, 256, 0, stream>>>(x, w, WEg, wn, out);
}

// Round 9
// 114.708 us; speedup vs baseline: 1.2598x; 1.2598x over previous
//
#include <hip/hip_runtime.h>
#include <float.h>

// VectorQuantizer: x [64,64,32,32] f32, weight [1024,64] f32
// out[n] = weight[argmin_k ||x_n - w_k||^2]
// score = 0.5||w||^2 + (-x).w via split-bf16 MFMA (6-step, lo*lo dropped).
// R22 = R21 structure with the launch bound FIXED: __launch_bounds__(256,3).
// R21 post-mortem: (256,4) => 128-reg budget < ~155 demand => K-loop scratch
// spill (VGPR_Count 64; FETCH 10.4->38MB, WRITE 16.4->55MB = scratch
// traffic; 86.6us). R18 measured this tile (areg[4][4]+acc[4][2]+b1/b2[16])
// at 112 total regs under (256,3) with NO spill => 170 budget fits with
// headroom. Register ladder for this kernel (measured): 64-code acc staged
// = 188 total (2 w/SIMD only); 32-code acc staged ~= 155 (3 w/SIMD at 170
// budget); 32-code acc direct-global = 112.
//   (1) CPK 64 (16 chunks): dbuf 2x16KB, LDS 37.9KB. Regs ~155 => 3
//       waves/SIMD, 3 blocks/CU = 12 waves/CU (1.5x R20's parallelism).
//       Same total MFMA (768/wave), folds, ds_reads, DMA bytes as R20;
//       16 half-size barrier drains instead of 8.
//   (2) Everything else = R20/R21: XOR-swizzled WEg staging (k&15==r16
//       invariant: rr = CH*32+ct*16+r16, kb multiple of 64), 6-step
//       product, short8 XE writes, redk-less epilogue, eps 7e-4+5e-5|B1|,
//       inline exact rescue.
// Checks: FETCH ~10.4MB (spill gone) / VGPR 130-160 / Occupancy ~19%.
#define NLAT   65536
#define KCODES 1024
#define DIM    64
#define HW     1024
#define LPB    128
#define CPK    64
#define NCHUNK 16
#define XROW   136          // XE padded row (shorts): 272 B

typedef float f32x4 __attribute__((ext_vector_type(4)));
typedef short short8 __attribute__((ext_vector_type(8)));

static __device__ __forceinline__ unsigned short f2bf(float f) {
    unsigned int u = __float_as_uint(f);
    return (unsigned short)((u + 0x7fffu + ((u >> 16) & 1u)) >> 16);   // RNE
}
static __device__ __forceinline__ float bf2f(unsigned short h) {
    return __uint_as_float(((unsigned int)h) << 16);
}
static __device__ __forceinline__ void async_cp16(const void* g, void* l) {
    __builtin_amdgcn_global_load_lds(
        (const __attribute__((address_space(1))) unsigned int*)g,
        (__attribute__((address_space(3))) unsigned int*)l, 16, 0, 0);
}

// ---------------------------------------------------------------------------
// Prep: one WAVE per code (grid 256 x 256 thr). Lane d loads w[k][d]
// (coalesced), shuffle-reduces the norm, writes hi/lo shorts into the
// XOR-swizzled row: logical seg L (L<8: hi, L>=8: lo), phys = L ^ (k & 15).
__global__ __launch_bounds__(256)
void vq_prep(const float* __restrict__ w, unsigned short* __restrict__ WEg,
             float* __restrict__ wn) {
    const int wave = threadIdx.x >> 6, lane = threadIdx.x & 63;
    const int k = blockIdx.x * 4 + wave;
    float v = w[(size_t)k * DIM + lane];
    float s = v * v;
    #pragma unroll
    for (int m = 32; m > 0; m >>= 1) s += __shfl_xor(s, m, 64);
    if (lane == 0) wn[k] = 0.5f * s;
    unsigned short h = f2bf(v);
    unsigned short l = f2bf(v - bf2f(h));
    unsigned short* row = WEg + (size_t)k * 128;
    const int j = lane & 7, Lh = lane >> 3, Ll = 8 + (lane >> 3);
    row[(((Lh ^ (k & 15)) << 3) | j)] = h;
    row[(((Ll ^ (k & 15)) << 3) | j)] = l;
}

// ---------------------------------------------------------------------------
// Main: 512 blocks x 256 thr (2 latent-halves x 2 code-halves). Wave tile
// 64 lats x 32 codes per 64-code chunk; A-frags (negated x) pinned in regs;
// B double-buffered in LDS via async DMA; inline exact rescue; gather.
__global__ __launch_bounds__(256, 3)
void vq_main(const float* __restrict__ x, const float* __restrict__ w,
             const unsigned short* __restrict__ WEg, const float* __restrict__ wn,
             float* __restrict__ out) {
    __shared__ __align__(16) char smem[37904];
    unsigned short* XE = (unsigned short*)smem;        // [128][136] (phase 0 only)
    char* wbuf0 = smem;                                // 16KB B buf (even chunks)
    char* wbuf1 = smem + 16384;                        // 16KB B buf (odd chunks)
    float* red  = (float*)smem;                        // [32][129] f32 (post-K)
    float* hb1  = (float*)(smem + 34816);              // [2][128] half-reduced score
    int*   hbk  = (int*)(smem + 35840);                // [2][128] half-reduced k
    int*   bfin = (int*)(smem + 36864);                // [128] winner k
    int*   amb  = (int*)(smem + 37376);                // [128] ambiguous lat ids
    int*   ambn = (int*)(smem + 37888);                // count

    const int tid  = threadIdx.x;
    const int wave = tid >> 6, lane = tid & 63;
    const int r16  = lane & 15, quad = lane >> 4;
    const int LH = wave & 1, CH = wave >> 1;   // CH: 32-code half of each 64-chunk

    const int blk = blockIdx.x;
    const int b   = blk >> 3;
    const int hw0 = (blk & 7) * LPB;

    if (tid == 0) ambn[0] = 0;

    // Phase 0: convert NEGATED x tile -> XE[lat][hi 0..63 | lo 64..127].
    {
        const int lat  = tid & 127;
        const int half = tid >> 7;
        const float* xb = x + (size_t)b * (DIM * HW) + hw0 + lat;
        #pragma unroll
        for (int g = 0; g < 4; ++g) {
            short8 hv, lv;
            #pragma unroll
            for (int j = 0; j < 8; ++j) {
                int chn = half * 32 + g * 8 + j;
                float v = -xb[chn * HW];          // negate: score = wn + (-x).w
                unsigned short h = f2bf(v);
                hv[j] = (short)h;
                lv[j] = (short)f2bf(v - bf2f(h));
            }
            *(short8*)&XE[lat * XROW + half * 32 + g * 8]      = hv;
            *(short8*)&XE[lat * XROW + 64 + half * 32 + g * 8] = lv;
        }
    }
    __syncthreads();

    // A-frags: span 0=hi d0-31, 1=hi d32-63, 2=lo d0-31, 3=lo d32-63
    short8 areg[4][4];
    #pragma unroll
    for (int lt = 0; lt < 4; ++lt)
        #pragma unroll
        for (int p = 0; p < 4; ++p)
            areg[lt][p] = *(const short8*)&XE[(LH * 64 + lt * 16 + r16) * XROW + p * 32 + quad * 8];
    __syncthreads();   // XE dead -> wbuf may overwrite

    // Prefetch chunk 0 into wbuf0 (drained by the first loop-top barrier)
    {
        const char* gsrc = (const char*)WEg + wave * 4096 + lane * 16;
        char* ldst = wbuf0 + wave * 4096;
        #pragma unroll
        for (int i = 0; i < 4; ++i) async_cp16(gsrc + i * 1024, ldst + i * 1024);
    }

    float b1[16], b2[16];
    #pragma unroll
    for (int sl = 0; sl < 16; ++sl) { b1[sl] = FLT_MAX; b2[sl] = FLT_MAX; }

    for (int ch = 0; ch < NCHUNK; ++ch) {
        __syncthreads();   // drains chunk-ch DMA (issued one full phase ago)
        if (ch + 1 < NCHUNK) {   // prefetch next chunk into the other buffer
            const char* gsrc = (const char*)WEg + (ch + 1) * 16384 + wave * 4096 + lane * 16;
            char* ldst = (((ch + 1) & 1) ? wbuf1 : wbuf0) + wave * 4096;
            #pragma unroll
            for (int i = 0; i < 4; ++i) async_cp16(gsrc + i * 1024, ldst + i * 1024);
        }
        const char* cbuf = (ch & 1) ? wbuf1 : wbuf0;
        const int kb = ch * CPK;

        float wnv[2] = {wn[kb + CH * 32 + r16], wn[kb + CH * 32 + 16 + r16]};
        f32x4 acc[4][2];
        #pragma unroll
        for (int lt = 0; lt < 4; ++lt)
            #pragma unroll
            for (int ct = 0; ct < 2; ++ct) {
                acc[lt][ct][0] = wnv[ct]; acc[lt][ct][1] = wnv[ct];
                acc[lt][ct][2] = wnv[ct]; acc[lt][ct][3] = wnv[ct];
            }

        // 6-step split product (lo*lo dropped; covered by rescue eps).
        // W spans: 0=hi d0-31, 1=hi d32-63, 2=lo d0-31, 3=lo d32-63.
        const int AI[6]  = {0, 1, 0, 2, 1, 3};
        const int WSp[6] = {2, 3, 0, 0, 1, 1};
        short8 bf[2];
        #pragma unroll
        for (int s = 0; s < 6; ++s) {
            if (s == 0 || WSp[s] != WSp[s - 1]) {
                #pragma unroll
                for (int ct = 0; ct < 2; ++ct) {
                    int rr = CH * 32 + ct * 16 + r16;      // row in chunk; k&15==r16
                    int seg = (WSp[s] * 4 + quad) ^ r16;   // matches prep swizzle
                    bf[ct] = *(const short8*)(cbuf + rr * 256 + seg * 16);
                }
            }
            #pragma unroll
            for (int lt = 0; lt < 4; ++lt)
                #pragma unroll
                for (int ct = 0; ct < 2; ++ct)
                    acc[lt][ct] = __builtin_amdgcn_mfma_f32_16x16x32_bf16(
                        areg[lt][AI[s]], bf[ct], acc[lt][ct], 0, 0, 0);
        }

        // Fold (4 ops/score): pack vid=(ch<<1)|ct in low 5 mantissa bits;
        // b2 = med3(b1,b2,p) exact top-2 update; b1 = min(b1,p).
        #pragma unroll
        for (int ct = 0; ct < 2; ++ct) {
            const unsigned vid = (unsigned)((ch << 1) | ct);
            #pragma unroll
            for (int lt = 0; lt < 4; ++lt)
                #pragma unroll
                for (int r = 0; r < 4; ++r) {
                    int sl = lt * 4 + r;
                    float p = __uint_as_float(
                        (__float_as_uint(acc[lt][ct][r]) & 0xFFFFFFE0u) | vid);
                    b2[sl] = __builtin_amdgcn_fmed3f(b1[sl], b2[sl], p);
                    b1[sl] = fminf(b1[sl], p);
                }
        }
    }

    // ---- Epilogue phase 1: argmin over 32 contributors per latent ----
    // Raw (vid-embedded) scores stored; k reconstructed from (vid,cid).
    // Any masked-score tie lands under eps => exact rescue.
    __syncthreads();   // wbuf dead -> red alias safe
    const int cid = CH * 16 + r16;   // 32 contributors per latent
    int kslot[16];
    #pragma unroll
    for (int lt = 0; lt < 4; ++lt)
        #pragma unroll
        for (int r = 0; r < 4; ++r) {
            int sl = lt * 4 + r;
            unsigned ub = __float_as_uint(b1[sl]);
            int vid = (int)(ub & 31u);
            kslot[sl] = (vid >> 1) * 64 + CH * 32 + (vid & 1) * 16 + r16;
            int lat = LH * 64 + lt * 16 + quad * 4 + r;
            red[cid * 129 + lat] = b1[sl];           // raw, vid kept
        }
    __syncthreads();
    // 2x-parallel: all 256 threads reduce 16 contributors each
    {
        const int lat = tid & 127, hf = tid >> 7;
        const int c0 = hf * 16;
        float s1 = red[c0 * 129 + lat]; int c1 = c0;
        #pragma unroll 4
        for (int c = 1; c < 16; ++c) {
            float s = red[(c0 + c) * 129 + lat];
            if (s < s1) { s1 = s; c1 = c0 + c; }
        }
        unsigned ub = __float_as_uint(s1);
        int vid = (int)(ub & 31u);
        hb1[hf * 128 + lat] = s1;
        hbk[hf * 128 + lat] = (vid >> 1) * 64 + (c1 >> 4) * 32 + (vid & 1) * 16 + (c1 & 15);
    }
    __syncthreads();
    float B1 = 0.f;
    if (tid < LPB) {
        float sA = hb1[tid];       int kA = hbk[tid];
        float sB = hb1[128 + tid]; int kB = hbk[128 + tid];
        if (sB < sA) { sA = sB; kA = kB; }
        B1 = sA; bfin[tid] = kA;
    }
    __syncthreads();
    // Phase 2: global 2nd best = min over (holder-of-winner-k ? b2 : b1)
    #pragma unroll
    for (int lt = 0; lt < 4; ++lt)
        #pragma unroll
        for (int r = 0; r < 4; ++r) {
            int sl = lt * 4 + r;
            int lat = LH * 64 + lt * 16 + quad * 4 + r;
            red[cid * 129 + lat] = (kslot[sl] == bfin[lat]) ? b2[sl] : b1[sl];
        }
    __syncthreads();
    {
        const int lat = tid & 127, hf = tid >> 7;
        float m = red[(hf * 16) * 129 + lat];
        #pragma unroll 4
        for (int c = 1; c < 16; ++c) m = fminf(m, red[(hf * 16 + c) * 129 + lat]);
        hb1[hf * 128 + lat] = m;
    }
    __syncthreads();
    if (tid < LPB) {
        float f2 = fminf(hb1[tid], hb1[128 + tid]);
        // eps: split double-rounding + fp32 accum + vid truncation + dropped
        // lo*lo term (<= ~1e-4 worst): base 7e-4, rel 5e-5.
        float eps = 7.0e-4f + 5.0e-5f * fabsf(B1);
        if (f2 - B1 < eps) {
            int pos = atomicAdd(ambn, 1);
            amb[pos] = tid;
        }
    }
    __syncthreads();

    // ---- Inline exact rescue: one wave per ambiguous latent ----
    {
        const int na = ambn[0];
        for (int e = wave; e < na; e += 4) {
            const int lat = amb[e];
            const float* xp = x + (size_t)b * (DIM * HW) + hw0 + lat;
            float xs[DIM];
            #pragma unroll
            for (int d = 0; d < DIM; ++d) xs[d] = xp[d * HW];  // wave-uniform
            float bb = FLT_MAX; int bi = 0;
            #pragma unroll 2
            for (int c = 0; c < 16; ++c) {
                int k = c * 64 + lane;
                const float4* wr = (const float4*)(w + (size_t)k * DIM);
                float a0 = 0.f, a1 = 0.f, a2 = 0.f, a3 = 0.f;
                #pragma unroll
                for (int j = 0; j < 16; ++j) {
                    float4 v = wr[j];
                    a0 += xs[4 * j]     * v.x;  a1 += xs[4 * j + 1] * v.y;
                    a2 += xs[4 * j + 2] * v.z;  a3 += xs[4 * j + 3] * v.w;
                }
                float s = wn[k] - ((a0 + a1) + (a2 + a3));
                if (s < bb) { bb = s; bi = k; }
            }
            #pragma unroll
            for (int off = 32; off > 0; off >>= 1) {   // lex (score,k) argmin
                float ob = __shfl_down(bb, off);
                int   oi = __shfl_down(bi, off);
                if (ob < bb || (ob == bb && oi < bi)) { bb = ob; bi = oi; }
            }
            if (lane == 0) bfin[lat] = bi;
        }
    }
    __syncthreads();

    // ---- Gather: out[n][:] = w[bfin][:]  (coalesced float4) ----
    float* outp = out + (size_t)blk * (LPB * DIM);
    #pragma unroll
    for (int r = 0; r < 8; ++r) {
        int idx = r * 256 + tid;
        int row = idx >> 4, seg = idx & 15;
        int code = bfin[row];
        *(float4*)&outp[idx * 4] = *(const float4*)&w[(size_t)code * DIM + seg * 4];
    }
}

extern "C" void kernel_launch(void* const* d_in, const int* in_sizes, int n_in,
                              void* d_out, int out_size, void* d_ws, size_t ws_size,
                              hipStream_t stream) {
    const float* x = (const float*)d_in[0];
    const float* w = (const float*)d_in[1];
    float* out = (float*)d_out;
    unsigned short* WEg = (unsigned short*)d_ws;                  // 262144 B (swizzled)
    float* wn = (float*)((char*)d_ws + 262144);                   // 4096 B

    vq_prep<<<KCODES / 4, 256, 0, stream>>>(w, WEg, wn);
    vq_main<<<NLAT / LPB, 256, 0, stream>>>(x, w, WEg, wn, out);
}

// Round 11
// 112.982 us; speedup vs baseline: 1.2790x; 1.0153x over previous
//
#include <hip/hip_runtime.h>
#include <float.h>

// VectorQuantizer: x [64,64,32,32] f32, weight [1024,64] f32
// out[n] = weight[argmin_k ||x_n - w_k||^2]
// score = 0.5||w||^2 + (-x).w via split-bf16 MFMA (6-step, lo*lo dropped).
// R23 (resubmit — R10 bench was GPUAcquisitionTimeout, never measured).
// Give the hardware blocks to schedule — GRID to 1024.
// R22 post-mortem: spill fixed (116 regs, FETCH 10.4MB) but occupancy
// unchanged 12.3% and 54us: grid 512 = 2 blocks/CU hard cap (the R19
// lesson, re-learned). LDS/regs allowed 4 blocks/CU; grid didn't.
//   (1) LPB 128->64: grid 1024 x 256 thr -> 4 blocks/CU. Wave tile
//       32 lats x 32 codes (LH=wave&1, CH=wave>>1): areg[2][4]+acc[2][2]
//       +b1/b2[8+8]+bf[2] ~ 100 regs -> 4 waves/SIMD in HW. All three
//       occupancy constraints (grid, LDS 35.3KB, regs) agree: 16 waves/CU,
//       2x R20/R22 parallelism. Device work invariant; DMA 256MB (~7us L2).
//   (2) Staged dbuf B unchanged: CPK=64, 2x16KB bufs, barrier-drained
//       prefetch one chunk ahead (R20-proven).
//   (3) Epilogue scaled: 32 contributors x 64 lats, red[32][65];
//       redk-less (k from vid+cid); eps 7e-4+5e-5|B1|; inline rescue.
//   (4) Swizzle invariant preserved: rr=CH*32+ct*16+r16, kb%64==0 =>
//       k&15==r16; seg=(span*4+quad)^r16.
// If occupancy up but dur >=50us: barrier drain is the bound -> next is
// counted-vmcnt deep prefetch on R20 structure.
#define NLAT   65536
#define KCODES 1024
#define DIM    64
#define HW     1024
#define LPB    64
#define CPK    64
#define NCHUNK 16
#define XROW   136          // XE padded row (shorts): 272 B

typedef float f32x4 __attribute__((ext_vector_type(4)));
typedef short short8 __attribute__((ext_vector_type(8)));

static __device__ __forceinline__ unsigned short f2bf(float f) {
    unsigned int u = __float_as_uint(f);
    return (unsigned short)((u + 0x7fffu + ((u >> 16) & 1u)) >> 16);   // RNE
}
static __device__ __forceinline__ float bf2f(unsigned short h) {
    return __uint_as_float(((unsigned int)h) << 16);
}
static __device__ __forceinline__ void async_cp16(const void* g, void* l) {
    __builtin_amdgcn_global_load_lds(
        (const __attribute__((address_space(1))) unsigned int*)g,
        (__attribute__((address_space(3))) unsigned int*)l, 16, 0, 0);
}

// ---------------------------------------------------------------------------
// Prep: one WAVE per code (grid 256 x 256 thr). Lane d loads w[k][d]
// (coalesced), shuffle-reduces the norm, writes hi/lo shorts into the
// XOR-swizzled row: logical seg L (L<8: hi, L>=8: lo), phys = L ^ (k & 15).
__global__ __launch_bounds__(256)
void vq_prep(const float* __restrict__ w, unsigned short* __restrict__ WEg,
             float* __restrict__ wn) {
    const int wave = threadIdx.x >> 6, lane = threadIdx.x & 63;
    const int k = blockIdx.x * 4 + wave;
    float v = w[(size_t)k * DIM + lane];
    float s = v * v;
    #pragma unroll
    for (int m = 32; m > 0; m >>= 1) s += __shfl_xor(s, m, 64);
    if (lane == 0) wn[k] = 0.5f * s;
    unsigned short h = f2bf(v);
    unsigned short l = f2bf(v - bf2f(h));
    unsigned short* row = WEg + (size_t)k * 128;
    const int j = lane & 7, Lh = lane >> 3, Ll = 8 + (lane >> 3);
    row[(((Lh ^ (k & 15)) << 3) | j)] = h;
    row[(((Ll ^ (k & 15)) << 3) | j)] = l;
}

// ---------------------------------------------------------------------------
// Main: 1024 blocks x 256 thr (2 lat-halves x 2 code-halves). Wave tile
// 32 lats x 32 codes per 64-code chunk; A-frags (negated x) pinned in regs;
// B double-buffered in LDS via async DMA; inline exact rescue; gather.
__global__ __launch_bounds__(256, 3)
void vq_main(const float* __restrict__ x, const float* __restrict__ w,
             const unsigned short* __restrict__ WEg, const float* __restrict__ wn,
             float* __restrict__ out) {
    __shared__ __align__(16) char smem[35332];
    unsigned short* XE = (unsigned short*)smem;        // [64][136] (phase 0 only, aliases wbufs)
    char* wbuf0 = smem;                                // 16KB B buf (even chunks)
    char* wbuf1 = smem + 16384;                        // 16KB B buf (odd chunks)
    float* red  = (float*)smem;                        // [32][65] f32 (post-K, aliases wbuf0)
    float* hb1  = (float*)(smem + 32768);              // [4][64] reduced score
    int*   hbk  = (int*)(smem + 33792);                // [4][64] reduced k
    int*   bfin = (int*)(smem + 34816);                // [64] winner k
    int*   amb  = (int*)(smem + 35072);                // [64] ambiguous lat ids
    int*   ambn = (int*)(smem + 35328);                // count

    const int tid  = threadIdx.x;
    const int wave = tid >> 6, lane = tid & 63;
    const int r16  = lane & 15, quad = lane >> 4;
    const int LH = wave & 1;          // lat half (32 lats)
    const int CH = wave >> 1;         // 32-code half of each 64-chunk

    const int blk = blockIdx.x;
    const int b   = blk >> 4;
    const int hw0 = (blk & 15) * LPB;

    if (tid == 0) ambn[0] = 0;

    // Phase 0: convert NEGATED x tile -> XE[lat][hi 0..63 | lo 64..127].
    // 256 threads: each does 16 channels of one latent, short8 LDS writes.
    {
        const int lat = tid & 63;
        const int grp = tid >> 6;     // 0..3
        const float* xb = x + (size_t)b * (DIM * HW) + hw0 + lat;
        #pragma unroll
        for (int g = 0; g < 2; ++g) {
            short8 hv, lv;
            #pragma unroll
            for (int j = 0; j < 8; ++j) {
                int chn = grp * 16 + g * 8 + j;
                float v = -xb[chn * HW];          // negate: score = wn + (-x).w
                unsigned short h = f2bf(v);
                hv[j] = (short)h;
                lv[j] = (short)f2bf(v - bf2f(h));
            }
            *(short8*)&XE[lat * XROW + grp * 16 + g * 8]      = hv;
            *(short8*)&XE[lat * XROW + 64 + grp * 16 + g * 8] = lv;
        }
    }
    __syncthreads();

    // A-frags: span 0=hi d0-31, 1=hi d32-63, 2=lo d0-31, 3=lo d32-63
    short8 areg[2][4];
    #pragma unroll
    for (int lt = 0; lt < 2; ++lt)
        #pragma unroll
        for (int p = 0; p < 4; ++p)
            areg[lt][p] = *(const short8*)&XE[(LH * 32 + lt * 16 + r16) * XROW + p * 32 + quad * 8];
    __syncthreads();   // XE dead -> wbuf may overwrite

    // Prefetch chunk 0 into wbuf0 (drained by the first loop-top barrier)
    {
        const char* gsrc = (const char*)WEg + wave * 4096 + lane * 16;
        char* ldst = wbuf0 + wave * 4096;
        #pragma unroll
        for (int i = 0; i < 4; ++i) async_cp16(gsrc + i * 1024, ldst + i * 1024);
    }

    float b1[8], b2[8];
    #pragma unroll
    for (int sl = 0; sl < 8; ++sl) { b1[sl] = FLT_MAX; b2[sl] = FLT_MAX; }

    for (int ch = 0; ch < NCHUNK; ++ch) {
        __syncthreads();   // drains chunk-ch DMA (issued one full phase ago)
        if (ch + 1 < NCHUNK) {   // prefetch next chunk into the other buffer
            const char* gsrc = (const char*)WEg + (ch + 1) * 16384 + wave * 4096 + lane * 16;
            char* ldst = (((ch + 1) & 1) ? wbuf1 : wbuf0) + wave * 4096;
            #pragma unroll
            for (int i = 0; i < 4; ++i) async_cp16(gsrc + i * 1024, ldst + i * 1024);
        }
        const char* cbuf = (ch & 1) ? wbuf1 : wbuf0;
        const int kb = ch * CPK;

        float wnv[2] = {wn[kb + CH * 32 + r16], wn[kb + CH * 32 + 16 + r16]};
        f32x4 acc[2][2];
        #pragma unroll
        for (int lt = 0; lt < 2; ++lt)
            #pragma unroll
            for (int ct = 0; ct < 2; ++ct) {
                acc[lt][ct][0] = wnv[ct]; acc[lt][ct][1] = wnv[ct];
                acc[lt][ct][2] = wnv[ct]; acc[lt][ct][3] = wnv[ct];
            }

        // 6-step split product (lo*lo dropped; covered by rescue eps).
        // W spans: 0=hi d0-31, 1=hi d32-63, 2=lo d0-31, 3=lo d32-63.
        const int AI[6]  = {0, 1, 0, 2, 1, 3};
        const int WSp[6] = {2, 3, 0, 0, 1, 1};
        short8 bf[2];
        #pragma unroll
        for (int s = 0; s < 6; ++s) {
            if (s == 0 || WSp[s] != WSp[s - 1]) {
                #pragma unroll
                for (int ct = 0; ct < 2; ++ct) {
                    int rr = CH * 32 + ct * 16 + r16;      // row in chunk; k&15==r16
                    int seg = (WSp[s] * 4 + quad) ^ r16;   // matches prep swizzle
                    bf[ct] = *(const short8*)(cbuf + rr * 256 + seg * 16);
                }
            }
            #pragma unroll
            for (int lt = 0; lt < 2; ++lt)
                #pragma unroll
                for (int ct = 0; ct < 2; ++ct)
                    acc[lt][ct] = __builtin_amdgcn_mfma_f32_16x16x32_bf16(
                        areg[lt][AI[s]], bf[ct], acc[lt][ct], 0, 0, 0);
        }

        // Fold (3 ops/score): pack vid=(ch<<1)|ct in low 5 mantissa bits;
        // b2 = med3(b1,b2,p) exact top-2 update; b1 = min(b1,p).
        #pragma unroll
        for (int ct = 0; ct < 2; ++ct) {
            const unsigned vid = (unsigned)((ch << 1) | ct);
            #pragma unroll
            for (int lt = 0; lt < 2; ++lt)
                #pragma unroll
                for (int r = 0; r < 4; ++r) {
                    int sl = lt * 4 + r;
                    float p = __uint_as_float(
                        (__float_as_uint(acc[lt][ct][r]) & 0xFFFFFFE0u) | vid);
                    b2[sl] = __builtin_amdgcn_fmed3f(b1[sl], b2[sl], p);
                    b1[sl] = fminf(b1[sl], p);
                }
        }
    }

    // ---- Epilogue phase 1: argmin over 32 contributors per latent ----
    // Raw (vid-embedded) scores stored; k reconstructed from (vid,cid).
    // Any masked-score tie lands under eps => exact rescue.
    __syncthreads();   // wbuf dead -> red alias safe
    const int cid = CH * 16 + r16;   // 32 contributors per latent
    int kslot[8];
    #pragma unroll
    for (int lt = 0; lt < 2; ++lt)
        #pragma unroll
        for (int r = 0; r < 4; ++r) {
            int sl = lt * 4 + r;
            unsigned ub = __float_as_uint(b1[sl]);
            int vid = (int)(ub & 31u);
            kslot[sl] = (vid >> 1) * 64 + CH * 32 + (vid & 1) * 16 + r16;
            int lat = LH * 32 + lt * 16 + quad * 4 + r;
            red[cid * 65 + lat] = b1[sl];            // raw, vid kept
        }
    __syncthreads();
    // 4x-parallel: 256 threads, 8 contributors each
    {
        const int lat = tid & 63, hf = tid >> 6;
        const int c0 = hf * 8;
        float s1 = red[c0 * 65 + lat]; int c1 = c0;
        #pragma unroll 4
        for (int c = 1; c < 8; ++c) {
            float s = red[(c0 + c) * 65 + lat];
            if (s < s1) { s1 = s; c1 = c0 + c; }
        }
        unsigned ub = __float_as_uint(s1);
        int vid = (int)(ub & 31u);
        hb1[hf * 64 + lat] = s1;
        hbk[hf * 64 + lat] = (vid >> 1) * 64 + (c1 >> 4) * 32 + (vid & 1) * 16 + (c1 & 15);
    }
    __syncthreads();
    float B1 = 0.f;
    if (tid < LPB) {
        float sA = hb1[tid]; int kA = hbk[tid];
        #pragma unroll
        for (int g = 1; g < 4; ++g) {
            float sB = hb1[g * 64 + tid];
            if (sB < sA) { sA = sB; kA = hbk[g * 64 + tid]; }
        }
        B1 = sA; bfin[tid] = kA;
    }
    __syncthreads();
    // Phase 2: global 2nd best = min over (holder-of-winner-k ? b2 : b1)
    #pragma unroll
    for (int lt = 0; lt < 2; ++lt)
        #pragma unroll
        for (int r = 0; r < 4; ++r) {
            int sl = lt * 4 + r;
            int lat = LH * 32 + lt * 16 + quad * 4 + r;
            red[cid * 65 + lat] = (kslot[sl] == bfin[lat]) ? b2[sl] : b1[sl];
        }
    __syncthreads();
    {
        const int lat = tid & 63, hf = tid >> 6;
        float m = red[(hf * 8) * 65 + lat];
        #pragma unroll 4
        for (int c = 1; c < 8; ++c) m = fminf(m, red[(hf * 8 + c) * 65 + lat]);
        hb1[hf * 64 + lat] = m;
    }
    __syncthreads();
    if (tid < LPB) {
        float f2 = fminf(fminf(hb1[tid], hb1[64 + tid]),
                         fminf(hb1[128 + tid], hb1[192 + tid]));
        // eps: split double-rounding + fp32 accum + vid truncation + dropped
        // lo*lo term (<= ~1e-4 worst): base 7e-4, rel 5e-5.
        float eps = 7.0e-4f + 5.0e-5f * fabsf(B1);
        if (f2 - B1 < eps) {
            int pos = atomicAdd(ambn, 1);
            amb[pos] = tid;
        }
    }
    __syncthreads();

    // ---- Inline exact rescue: one wave per ambiguous latent ----
    {
        const int na = ambn[0];
        for (int e = wave; e < na; e += 4) {
            const int lat = amb[e];
            const float* xp = x + (size_t)b * (DIM * HW) + hw0 + lat;
            float xs[DIM];
            #pragma unroll
            for (int d = 0; d < DIM; ++d) xs[d] = xp[d * HW];  // wave-uniform
            float bb = FLT_MAX; int bi = 0;
            #pragma unroll 2
            for (int c = 0; c < 16; ++c) {
                int k = c * 64 + lane;
                const float4* wr = (const float4*)(w + (size_t)k * DIM);
                float a0 = 0.f, a1 = 0.f, a2 = 0.f, a3 = 0.f;
                #pragma unroll
                for (int j = 0; j < 16; ++j) {
                    float4 v = wr[j];
                    a0 += xs[4 * j]     * v.x;  a1 += xs[4 * j + 1] * v.y;
                    a2 += xs[4 * j + 2] * v.z;  a3 += xs[4 * j + 3] * v.w;
                }
                float s = wn[k] - ((a0 + a1) + (a2 + a3));
                if (s < bb) { bb = s; bi = k; }
            }
            #pragma unroll
            for (int off = 32; off > 0; off >>= 1) {   // lex (score,k) argmin
                float ob = __shfl_down(bb, off);
                int   oi = __shfl_down(bi, off);
                if (ob < bb || (ob == bb && oi < bi)) { bb = ob; bi = oi; }
            }
            if (lane == 0) bfin[lat] = bi;
        }
    }
    __syncthreads();

    // ---- Gather: out[n][:] = w[bfin][:]  (coalesced float4) ----
    float* outp = out + (size_t)blk * (LPB * DIM);
    #pragma unroll
    for (int r = 0; r < 4; ++r) {
        int idx = r * 256 + tid;
        int row = idx >> 4, seg = idx & 15;
        int code = bfin[row];
        *(float4*)&outp[idx * 4] = *(const float4*)&w[(size_t)code * DIM + seg * 4];
    }
}

extern "C" void kernel_launch(void* const* d_in, const int* in_sizes, int n_in,
                              void* d_out, int out_size, void* d_ws, size_t ws_size,
                              hipStream_t stream) {
    const float* x = (const float*)d_in[0];
    const float* w = (const float*)d_in[1];
    float* out = (float*)d_out;
    unsigned short* WEg = (unsigned short*)d_ws;                  // 262144 B (swizzled)
    float* wn = (float*)((char*)d_ws + 262144);                   // 4096 B

    vq_prep<<<KCODES / 4, 256, 0, stream>>>(w, WEg, wn);
    vq_main<<<NLAT / LPB, 256, 0, stream>>>(x, w, WEg, wn, out);
}

// Round 12
// 105.415 us; speedup vs baseline: 1.3708x; 1.0718x over previous
//
#include <hip/hip_runtime.h>
#include <float.h>

// VectorQuantizer: x [64,64,32,32] f32, weight [1024,64] f32
// out[n] = weight[argmin_k ||x_n - w_k||^2]
// score = 0.5||w||^2 + (-x).w via split-bf16 MFMA (6-step, lo*lo dropped).
// R24 = R20 (best, 48.5us) + rescue-volume cut + K-loop cleanup.
// R23 post-mortem: occupancy 12->20% with dur FLAT (53.3); R20-R23 show
// per-chunk time ~ per-CU work, invariant to occupancy AND DMA volume,
// all pipes at 5-10% of ceiling => K-loop roofline model wrong; hidden
// serial cost outside the loop accounting. Prime suspect: exact rescue
// (16 chunk-iters x 16 scattered float4 w-rows/lane ~ 8-16k cy/latent),
// whose VOLUME is set by eps ~ 2-3e-3 at |B1|~40 — 10-20x the justified
// error bound (split residual ~1.2e-4 + lo*lo ~3e-5 + trunc 2e-6|B1|).
// Codes with gap > bound are provably correct WITHOUT rescue.
//   (1) eps: 7e-4+5e-5|B1| -> 5e-4+1e-5|B1| (~3-4x fewer rescued latents;
//       still >=3x the analyzed error bound — correctness preserved).
//   (2) wn staged to LDS (wnl[1024], 4KB): K-loop vmem = DMA only.
//   (3) #pragma unroll 2 on K-loop: buffer select + addressing fold.
// Everything else identical to R20: 512x256, LPB=128, CPK=128, 8 chunks,
// XOR-swizzled staging dbuf, 6-step product, short8 XE, redk-less epilogue.
#define NLAT   65536
#define KCODES 1024
#define DIM    64
#define HW     1024
#define LPB    128
#define CPK    128
#define NCHUNK 8
#define XROW   136          // XE padded row (shorts): 272 B

typedef float f32x4 __attribute__((ext_vector_type(4)));
typedef short short8 __attribute__((ext_vector_type(8)));

static __device__ __forceinline__ unsigned short f2bf(float f) {
    unsigned int u = __float_as_uint(f);
    return (unsigned short)((u + 0x7fffu + ((u >> 16) & 1u)) >> 16);   // RNE
}
static __device__ __forceinline__ float bf2f(unsigned short h) {
    return __uint_as_float(((unsigned int)h) << 16);
}
static __device__ __forceinline__ void async_cp16(const void* g, void* l) {
    __builtin_amdgcn_global_load_lds(
        (const __attribute__((address_space(1))) unsigned int*)g,
        (__attribute__((address_space(3))) unsigned int*)l, 16, 0, 0);
}

// ---------------------------------------------------------------------------
// Prep: one WAVE per code (grid 256 x 256 thr). Lane d loads w[k][d]
// (coalesced), shuffle-reduces the norm, writes hi/lo shorts into the
// XOR-swizzled row: logical seg L (L<8: hi, L>=8: lo), phys = L ^ (k & 15).
__global__ __launch_bounds__(256)
void vq_prep(const float* __restrict__ w, unsigned short* __restrict__ WEg,
             float* __restrict__ wn) {
    const int wave = threadIdx.x >> 6, lane = threadIdx.x & 63;
    const int k = blockIdx.x * 4 + wave;
    float v = w[(size_t)k * DIM + lane];
    float s = v * v;
    #pragma unroll
    for (int m = 32; m > 0; m >>= 1) s += __shfl_xor(s, m, 64);
    if (lane == 0) wn[k] = 0.5f * s;
    unsigned short h = f2bf(v);
    unsigned short l = f2bf(v - bf2f(h));
    unsigned short* row = WEg + (size_t)k * 128;
    const int j = lane & 7, Lh = lane >> 3, Ll = 8 + (lane >> 3);
    row[(((Lh ^ (k & 15)) << 3) | j)] = h;
    row[(((Ll ^ (k & 15)) << 3) | j)] = l;
}

// ---------------------------------------------------------------------------
// Main: 512 blocks x 256 thr (2 latent-halves x 2 code-halves). Wave tile
// 64 lats x 64 codes per 128-code chunk; A-frags (negated x) pinned in regs;
// B double-buffered in LDS via async DMA; inline exact rescue; gather.
__global__ __launch_bounds__(256, 2)
void vq_main(const float* __restrict__ x, const float* __restrict__ w,
             const unsigned short* __restrict__ WEg, const float* __restrict__ wn,
             float* __restrict__ out) {
    __shared__ __align__(16) char smem[70672];
    unsigned short* XE = (unsigned short*)smem;        // [128][136] (phase 0 only)
    char* wbuf0 = smem;                                // 32KB B buf (even chunks)
    char* wbuf1 = smem + 32768;                        // 32KB B buf (odd chunks)
    float* red  = (float*)smem;                        // [32][129] f32 (post-K)
    float* hb1  = (float*)(smem + 33024);              // [2][128] half-reduced score
    int*   hbk  = (int*)(smem + 34048);                // [2][128] half-reduced k
    int*   bfin = (int*)(smem + 65536);                // [128] winner k
    int*   amb  = (int*)(smem + 66048);                // [128] ambiguous lat ids
    int*   ambn = (int*)(smem + 66560);                // count
    float* wnl  = (float*)(smem + 66576);              // [1024] 0.5||w||^2 (whole kernel)

    const int tid  = threadIdx.x;
    const int wave = tid >> 6, lane = tid & 63;
    const int r16  = lane & 15, quad = lane >> 4;
    const int LH = wave & 1, CH = wave >> 1;

    const int blk = blockIdx.x;
    const int b   = blk >> 3;
    const int hw0 = (blk & 7) * LPB;

    if (tid == 0) ambn[0] = 0;

    // Phase 0a: stage wn -> LDS (K-loop then has zero non-DMA vmem).
    wnl[tid]       = wn[tid];
    wnl[tid + 256] = wn[tid + 256];
    wnl[tid + 512] = wn[tid + 512];
    wnl[tid + 768] = wn[tid + 768];

    // Phase 0b: convert NEGATED x tile -> XE[lat][hi 0..63 | lo 64..127].
    {
        const int lat  = tid & 127;
        const int half = tid >> 7;
        const float* xb = x + (size_t)b * (DIM * HW) + hw0 + lat;
        #pragma unroll
        for (int g = 0; g < 4; ++g) {
            short8 hv, lv;
            #pragma unroll
            for (int j = 0; j < 8; ++j) {
                int chn = half * 32 + g * 8 + j;
                float v = -xb[chn * HW];          // negate: score = wn + (-x).w
                unsigned short h = f2bf(v);
                hv[j] = (short)h;
                lv[j] = (short)f2bf(v - bf2f(h));
            }
            *(short8*)&XE[lat * XROW + half * 32 + g * 8]      = hv;
            *(short8*)&XE[lat * XROW + 64 + half * 32 + g * 8] = lv;
        }
    }
    __syncthreads();

    // A-frags: span 0=hi d0-31, 1=hi d32-63, 2=lo d0-31, 3=lo d32-63
    short8 areg[4][4];
    #pragma unroll
    for (int lt = 0; lt < 4; ++lt)
        #pragma unroll
        for (int p = 0; p < 4; ++p)
            areg[lt][p] = *(const short8*)&XE[(LH * 64 + lt * 16 + r16) * XROW + p * 32 + quad * 8];
    __syncthreads();   // XE dead -> wbuf may overwrite

    // Prefetch chunk 0 into wbuf0 (drained by the first loop-top barrier)
    {
        const char* gsrc = (const char*)WEg + wave * 8192 + lane * 16;
        char* ldst = wbuf0 + wave * 8192;
        #pragma unroll
        for (int i = 0; i < 8; ++i) async_cp16(gsrc + i * 1024, ldst + i * 1024);
    }

    float b1[16], b2[16];
    #pragma unroll
    for (int sl = 0; sl < 16; ++sl) { b1[sl] = FLT_MAX; b2[sl] = FLT_MAX; }

    #pragma unroll 2
    for (int ch = 0; ch < NCHUNK; ++ch) {
        __syncthreads();   // drains chunk-ch DMA (issued one full phase ago)
        if (ch + 1 < NCHUNK) {   // prefetch next chunk into the other buffer
            const char* gsrc = (const char*)WEg + (ch + 1) * 32768 + wave * 8192 + lane * 16;
            char* ldst = (((ch + 1) & 1) ? wbuf1 : wbuf0) + wave * 8192;
            #pragma unroll
            for (int i = 0; i < 8; ++i) async_cp16(gsrc + i * 1024, ldst + i * 1024);
        }
        const char* cbuf = (ch & 1) ? wbuf1 : wbuf0;
        const int kb = ch * CPK;

        float wnv[4];
        #pragma unroll
        for (int ct = 0; ct < 4; ++ct)
            wnv[ct] = wnl[kb + CH * 64 + ct * 16 + r16];
        f32x4 acc[4][4];
        #pragma unroll
        for (int lt = 0; lt < 4; ++lt)
            #pragma unroll
            for (int ct = 0; ct < 4; ++ct) {
                acc[lt][ct][0] = wnv[ct]; acc[lt][ct][1] = wnv[ct];
                acc[lt][ct][2] = wnv[ct]; acc[lt][ct][3] = wnv[ct];
            }

        // 6-step split product (lo*lo dropped; covered by rescue eps).
        // W spans: 0=hi d0-31, 1=hi d32-63, 2=lo d0-31, 3=lo d32-63.
        const int AI[6]  = {0, 1, 0, 2, 1, 3};
        const int WSp[6] = {2, 3, 0, 0, 1, 1};
        short8 bf[4];
        #pragma unroll
        for (int s = 0; s < 6; ++s) {
            if (s == 0 || WSp[s] != WSp[s - 1]) {
                #pragma unroll
                for (int ct = 0; ct < 4; ++ct) {
                    int r = CH * 64 + ct * 16 + r16;
                    int seg = (WSp[s] * 4 + quad) ^ r16;   // matches prep swizzle
                    bf[ct] = *(const short8*)(cbuf + r * 256 + seg * 16);
                }
            }
            #pragma unroll
            for (int lt = 0; lt < 4; ++lt)
                #pragma unroll
                for (int ct = 0; ct < 4; ++ct)
                    acc[lt][ct] = __builtin_amdgcn_mfma_f32_16x16x32_bf16(
                        areg[lt][AI[s]], bf[ct], acc[lt][ct], 0, 0, 0);
        }

        // Fold (3 ops/score): pack vid=(ch<<2)|ct in low 5 mantissa bits;
        // b2 = med3(b1,b2,p) exact top-2 update; b1 = min(b1,p).
        #pragma unroll
        for (int ct = 0; ct < 4; ++ct) {
            const unsigned vid = (unsigned)((ch << 2) | ct);
            #pragma unroll
            for (int lt = 0; lt < 4; ++lt)
                #pragma unroll
                for (int r = 0; r < 4; ++r) {
                    int sl = lt * 4 + r;
                    float p = __uint_as_float(
                        (__float_as_uint(acc[lt][ct][r]) & 0xFFFFFFE0u) | vid);
                    b2[sl] = __builtin_amdgcn_fmed3f(b1[sl], b2[sl], p);
                    b1[sl] = fminf(b1[sl], p);
                }
        }
    }

    // ---- Epilogue phase 1: argmin over 32 contributors per latent ----
    // Raw (vid-embedded) scores stored; k reconstructed from (vid,cid).
    // Any masked-score tie lands under eps => exact rescue.
    __syncthreads();   // wbuf dead -> red alias safe
    const int cid = CH * 16 + r16;   // 32 contributors per latent
    int kslot[16];
    #pragma unroll
    for (int lt = 0; lt < 4; ++lt)
        #pragma unroll
        for (int r = 0; r < 4; ++r) {
            int sl = lt * 4 + r;
            unsigned ub = __float_as_uint(b1[sl]);
            int vid = (int)(ub & 31u);
            kslot[sl] = (vid >> 2) * 128 + CH * 64 + (vid & 3) * 16 + r16;
            int lat = LH * 64 + lt * 16 + quad * 4 + r;
            red[cid * 129 + lat] = b1[sl];           // raw, vid kept
        }
    __syncthreads();
    // 2x-parallel: all 256 threads reduce 16 contributors each
    {
        const int lat = tid & 127, hf = tid >> 7;
        const int c0 = hf * 16;
        float s1 = red[c0 * 129 + lat]; int c1 = c0;
        #pragma unroll 4
        for (int c = 1; c < 16; ++c) {
            float s = red[(c0 + c) * 129 + lat];
            if (s < s1) { s1 = s; c1 = c0 + c; }
        }
        unsigned ub = __float_as_uint(s1);
        int vid = (int)(ub & 31u);
        hb1[hf * 128 + lat] = s1;
        hbk[hf * 128 + lat] = (vid >> 2) * 128 + (c1 >> 4) * 64 + (vid & 3) * 16 + (c1 & 15);
    }
    __syncthreads();
    float B1 = 0.f;
    if (tid < LPB) {
        float sA = hb1[tid];       int kA = hbk[tid];
        float sB = hb1[128 + tid]; int kB = hbk[128 + tid];
        if (sB < sA) { sA = sB; kA = kB; }
        B1 = sA; bfin[tid] = kA;
    }
    __syncthreads();
    // Phase 2: global 2nd best = min over (holder-of-winner-k ? b2 : b1)
    #pragma unroll
    for (int lt = 0; lt < 4; ++lt)
        #pragma unroll
        for (int r = 0; r < 4; ++r) {
            int sl = lt * 4 + r;
            int lat = LH * 64 + lt * 16 + quad * 4 + r;
            red[cid * 129 + lat] = (kslot[sl] == bfin[lat]) ? b2[sl] : b1[sl];
        }
    __syncthreads();
    {
        const int lat = tid & 127, hf = tid >> 7;
        float m = red[(hf * 16) * 129 + lat];
        #pragma unroll 4
        for (int c = 1; c < 16; ++c) m = fminf(m, red[(hf * 16 + c) * 129 + lat]);
        hb1[hf * 128 + lat] = m;
    }
    __syncthreads();
    if (tid < LPB) {
        float f2 = fminf(hb1[tid], hb1[128 + tid]);
        // eps: JUSTIFIED error budget of the 6-step split product:
        // split double-rounding residual ~1.2e-4 + dropped lo*lo ~3e-5 typ
        // + vid trunc 2e-6|B1| + fp32 accum 1e-6|B1|. 5e-4+1e-5|B1| is
        // >=3x that bound. (Was 7e-4+5e-5|B1| ~ 2-3e-3 — 10-20x too wide,
        // rescuing provably-correct latents.)
        float eps = 5.0e-4f + 1.0e-5f * fabsf(B1);
        if (f2 - B1 < eps) {
            int pos = atomicAdd(ambn, 1);
            amb[pos] = tid;
        }
    }
    __syncthreads();

    // ---- Inline exact rescue: one wave per ambiguous latent ----
    {
        const int na = ambn[0];
        for (int e = wave; e < na; e += 4) {
            const int lat = amb[e];
            const float* xp = x + (size_t)b * (DIM * HW) + hw0 + lat;
            float xs[DIM];
            #pragma unroll
            for (int d = 0; d < DIM; ++d) xs[d] = xp[d * HW];  // wave-uniform
            float bb = FLT_MAX; int bi = 0;
            #pragma unroll 2
            for (int c = 0; c < 16; ++c) {
                int k = c * 64 + lane;
                const float4* wr = (const float4*)(w + (size_t)k * DIM);
                float a0 = 0.f, a1 = 0.f, a2 = 0.f, a3 = 0.f;
                #pragma unroll
                for (int j = 0; j < 16; ++j) {
                    float4 v = wr[j];
                    a0 += xs[4 * j]     * v.x;  a1 += xs[4 * j + 1] * v.y;
                    a2 += xs[4 * j + 2] * v.z;  a3 += xs[4 * j + 3] * v.w;
                }
                float s = wn[k] - ((a0 + a1) + (a2 + a3));
                if (s < bb) { bb = s; bi = k; }
            }
            #pragma unroll
            for (int off = 32; off > 0; off >>= 1) {   // lex (score,k) argmin
                float ob = __shfl_down(bb, off);
                int   oi = __shfl_down(bi, off);
                if (ob < bb || (ob == bb && oi < bi)) { bb = ob; bi = oi; }
            }
            if (lane == 0) bfin[lat] = bi;
        }
    }
    __syncthreads();

    // ---- Gather: out[n][:] = w[bfin][:]  (coalesced float4) ----
    float* outp = out + (size_t)blk * (LPB * DIM);
    #pragma unroll
    for (int r = 0; r < 8; ++r) {
        int idx = r * 256 + tid;
        int row = idx >> 4, seg = idx & 15;
        int code = bfin[row];
        *(float4*)&outp[idx * 4] = *(const float4*)&w[(size_t)code * DIM + seg * 4];
    }
}

extern "C" void kernel_launch(void* const* d_in, const int* in_sizes, int n_in,
                              void* d_out, int out_size, void* d_ws, size_t ws_size,
                              hipStream_t stream) {
    const float* x = (const float*)d_in[0];
    const float* w = (const float*)d_in[1];
    float* out = (float*)d_out;
    unsigned short* WEg = (unsigned short*)d_ws;                  // 262144 B (swizzled)
    float* wn = (float*)((char*)d_ws + 262144);                   // 4096 B

    vq_prep<<<KCODES / 4, 256, 0, stream>>>(w, WEg, wn);
    vq_main<<<NLAT / LPB, 256, 0, stream>>>(x, w, WEg, wn, out);
}